// Round 14
// baseline (190.042 us; speedup 1.0000x reference)
//
#include <hip/hip_runtime.h>
#include <math.h>

#define NN   100000
#define NE   1600000
#define INC  32
#define HID  64
#define OUTC 40
#define NBUCK 391          // ceil(NN/256) coarse dst-buckets (256 nodes each)
#define BCAP  5120         // slab capacity per bucket (mean 4096, +16 sigma)

typedef short bf16x8 __attribute__((ext_vector_type(8)));
typedef float f32x4  __attribute__((ext_vector_type(4)));
typedef float v2f    __attribute__((ext_vector_type(2)));
typedef _Float16 f16x2 __attribute__((ext_vector_type(2)));

// bf16 helpers (round-to-nearest-even)
__device__ inline unsigned f2bf(float f) {
    unsigned u = __float_as_uint(f);
    return (u + 0x7fffu + ((u >> 16) & 1u)) >> 16;
}
__device__ inline unsigned packbf(float a, float b) {
    return f2bf(a) | (f2bf(b) << 16);
}
__device__ inline ushort f2h(float f) {
    return __builtin_bit_cast(unsigned short, (_Float16)f);
}
__device__ inline f16x2 u2h(unsigned u) { return __builtin_bit_cast(f16x2, u); }

// payload decode: src in bits 0-16, p (15-bit fixed) in bits 17-31
__device__ inline int   pdec_s(unsigned v) { return (int)(v & 0x1FFFFu); }
__device__ inline float pdec_p(unsigned v) { return (float)(v >> 17) * (1.0f / 32767.0f); }

// shuffle a packed f32 pair
__device__ inline v2f sh2(v2f a, int src) {
    v2f r;
    r.x = __shfl(a.x, src & 63);
    r.y = __shfl(a.y, src & 63);
    return r;
}

// ---------------------------------------------------------------------------
// Binning pass: block-local histogram + one global atomicAdd per bucket per
// block, then run-writes of 8B payloads into per-bucket slabs.
// ---------------------------------------------------------------------------
__global__ __launch_bounds__(256) void k_bin(
    const int* __restrict__ src, const int* __restrict__ dst,
    const float* __restrict__ pseudo,
    int* __restrict__ gcur, uint2* __restrict__ slab)
{
    __shared__ int lh[NBUCK];
    __shared__ int lb[NBUCK];
    int t = threadIdx.x;
    for (int i = t; i < NBUCK; i += 256) lh[i] = 0;
    __syncthreads();

    int base = blockIdx.x * 4096;
#pragma unroll
    for (int i = 0; i < 16; i++) {
        int e = base + i * 256 + t;
        if (e < NE) atomicAdd(&lh[dst[e] >> 8], 1);
    }
    __syncthreads();
    for (int i = t; i < NBUCK; i += 256) {
        int c = lh[i];
        lb[i] = c ? atomicAdd(&gcur[i], c) : 0;
        lh[i] = 0;
    }
    __syncthreads();
#pragma unroll
    for (int i = 0; i < 16; i++) {
        int e = base + i * 256 + t;
        if (e < NE) {
            int d = dst[e];
            int b = d >> 8;
            int loc = atomicAdd(&lh[b], 1);
            unsigned pq = (unsigned)__float2int_rn(pseudo[e] * 32767.0f);
            slab[(size_t)b * BCAP + lb[b] + loc] =
                make_uint2((unsigned)src[e] | (pq << 17), (unsigned)(d & 255));
        }
    }
}

// exclusive scan of bucket sizes (one block)
__global__ __launch_bounds__(512) void k_bscan(const int* __restrict__ gcur,
                                               int* __restrict__ bbase)
{
    __shared__ int tmp[512];
    int t = threadIdx.x;
    int v = (t < NBUCK) ? gcur[t] : 0;
    tmp[t] = v;
    __syncthreads();
    for (int off = 1; off < 512; off <<= 1) {
        int add = (t >= off) ? tmp[t - off] : 0;
        __syncthreads();
        tmp[t] += add;
        __syncthreads();
    }
    if (t < NBUCK) bbase[t] = tmp[t] - v;
}

// Per-bucket CSR finalize: counts, offsets, and dst-ordered 4B payloads.
__global__ __launch_bounds__(256) void k_csr(
    const uint2* __restrict__ slab, const int* __restrict__ gcur,
    const int* __restrict__ bbase,
    int* __restrict__ cnt, int* __restrict__ offs, unsigned* __restrict__ pay)
{
    __shared__ int cl[256], ol[256], cur[256];
    __shared__ int ssz, sbase;
    int b = blockIdx.x, t = threadIdx.x;
    if (t == 0) { ssz = gcur[b]; sbase = bbase[b]; }
    cl[t] = 0;
    __syncthreads();
    int sz = ssz, base0 = sbase;
    const uint2* sl = slab + (size_t)b * BCAP;

    for (int i = t; i < sz; i += 256) atomicAdd(&cl[sl[i].y], 1);
    __syncthreads();

    int v = cl[t];
    ol[t] = v;
    __syncthreads();
    for (int off = 1; off < 256; off <<= 1) {
        int add = (t >= off) ? ol[t - off] : 0;
        __syncthreads();
        ol[t] += add;
        __syncthreads();
    }
    int excl = ol[t] - v;
    __syncthreads();
    ol[t] = excl;
    cur[t] = 0;
    int node = b * 256 + t;
    if (node < NN) { cnt[node] = v; offs[node] = base0 + excl; }
    __syncthreads();

    for (int i = t; i < sz; i += 256) {
        uint2 v2 = sl[i];
        int loc = atomicAdd(&cur[v2.y], 1);
        pay[base0 + ol[v2.y] + loc] = v2.x;
    }
}

// ---------------------------------------------------------------------------
// Merged prep: x -> fp8 rows (32 B/row, row NN zeroed) + weight transposes.
//  W1T[64][96]: k<32 -> W1[0]; 32<=k<64 -> W1[1]-W1[0]; k>=64 -> root1 (^T)
//  W2T[128][64]: col j<80: o=(j>>3)*4+(j&3); (j&7)<4 -> W2[0][:,o],
//                else W2[1][:,o]-W2[0][:,o]; 80..119: root2; 120..127: 0
// ---------------------------------------------------------------------------
__global__ __launch_bounds__(256) void k_prep(
    const float* __restrict__ x,
    const float* __restrict__ W1, const float* __restrict__ root1,
    const float* __restrict__ W2, const float* __restrict__ root2,
    unsigned* __restrict__ xq, ushort* __restrict__ W1T,
    ushort* __restrict__ W2T)
{
    int i = blockIdx.x * 256 + threadIdx.x;
    if (i < (NN + 1) * 8) {
        unsigned u = 0;
        if (i < NN * 8) {
            float4 v = ((const float4*)x)[i];
            u = __builtin_amdgcn_cvt_pk_fp8_f32(v.x, v.y, 0, false);
            u = __builtin_amdgcn_cvt_pk_fp8_f32(v.z, v.w, u, true);
        }
        xq[i] = u;
        return;
    }
    int j = i - (NN + 1) * 8;
    if (j >= 0 && j < 64 * 96) {
        int o = j / 96, k = j % 96;
        float v;
        if (k < 32)      v = W1[k * HID + o];
        else if (k < 64) v = W1[INC * HID + (k - 32) * HID + o] - W1[(k - 32) * HID + o];
        else             v = root1[(k - 64) * HID + o];
        W1T[j] = (ushort)f2bf(v);
    }
    int j2 = j - 64 * 96;
    if (j2 >= 0 && j2 < 128 * 64) {
        int jj = j2 / 64, k = j2 % 64;
        float v = 0.0f;
        if (jj < 80) {
            int o = (jj >> 3) * 4 + (jj & 3);
            float g0 = W2[k * OUTC + o];
            v = ((jj & 7) < 4) ? g0 : (W2[HID * OUTC + k * OUTC + o] - g0);
        } else if (jj < 120) {
            v = root2[k * OUTC + (jj - 80)];
        }
        W2T[j2] = (ushort)f2bf(v);
    }
}

// ---------------------------------------------------------------------------
// Layer 1 gather (R9 form): wave per node, 8 edges per vmem instruction; lane
// reads one dword = 4 fp8 feats. S=sum(x), T=sum(p*x) in packed f32.
// Apre = [S*inv | T*inv | x(f32 source)] (bf16).
// ---------------------------------------------------------------------------
__global__ __launch_bounds__(256) void k_agg1(
    const unsigned* __restrict__ xq, const unsigned* __restrict__ pay,
    const int* __restrict__ offs, const int* __restrict__ cnt,
    const float* __restrict__ x, ushort* __restrict__ Apre)
{
    int t = threadIdx.x;
    int w = t >> 6, lane = t & 63;
    int slot = lane >> 3, sub = lane & 7;

    for (int n0 = blockIdx.x * 4; n0 < NN; n0 += gridDim.x * 4) {
        int n = n0 + w;
        int e0 = offs[n], c = cnt[n];

        v2f S01 = {0.f, 0.f}, S23 = {0.f, 0.f};
        v2f T01 = {0.f, 0.f}, T23 = {0.f, 0.f};

        for (int base = 0; base < c; base += 64) {
            int bc = min(c - base, 64);
            int li = (lane < bc) ? lane : (bc - 1);
            unsigned pl = pay[e0 + base + li];
            for (int g = 0; g < bc; g += 8) {
                int je = g + slot;                       // <= 63
                unsigned v = (unsigned)__shfl((int)pl, je);
                int sj = (je < bc) ? pdec_s(v) : NN;     // invalid -> zero row
                float pj = pdec_p(v);
                v2f pp = {pj, pj};
                unsigned gv = xq[sj * 8 + sub];
                v2f v01 = __builtin_amdgcn_cvt_pk_f32_fp8(gv, false);
                v2f v23 = __builtin_amdgcn_cvt_pk_f32_fp8(gv, true);
                S01 += v01; S23 += v23;
                T01 = __builtin_elementwise_fma(pp, v01, T01);
                T23 = __builtin_elementwise_fma(pp, v23, T23);
            }
        }

        // butterfly over 8 slots (lane bits 3..5)
#pragma unroll
        for (int mask = 8; mask <= 32; mask <<= 1) {
            S01.x += __shfl_xor(S01.x, mask); S01.y += __shfl_xor(S01.y, mask);
            S23.x += __shfl_xor(S23.x, mask); S23.y += __shfl_xor(S23.y, mask);
            T01.x += __shfl_xor(T01.x, mask); T01.y += __shfl_xor(T01.y, mask);
            T23.x += __shfl_xor(T23.x, mask); T23.y += __shfl_xor(T23.y, mask);
        }
        if (slot == 0) {
            float inv = 1.0f / fmaxf((float)c, 1.0f);
            ushort* ap = Apre + (size_t)n * 96;
            *(uint2*)(ap + sub * 4) = make_uint2(
                packbf(S01.x * inv, S01.y * inv), packbf(S23.x * inv, S23.y * inv));
            *(uint2*)(ap + 32 + sub * 4) = make_uint2(
                packbf(T01.x * inv, T01.y * inv), packbf(T23.x * inv, T23.y * inv));
            float4 xv = *((const float4*)(x + (size_t)n * INC) + sub);
            *(uint2*)(ap + 64 + sub * 4) = make_uint2(
                packbf(xv.x, xv.y), packbf(xv.z, xv.w));
        }
    }
}

// ---------------------------------------------------------------------------
// Node transform on MFMA: 64 nodes/block, 4 waves x 16-node M-tiles.
// GEMM1 -> h (bf16 LDS); GEMM2 -> hwq (fp8 interleaved [g0-quad|d-quad], 80B
// rows) + rtb (packed f16 pairs of h@root2+b2, 80B rows), via LDS staging.
// ---------------------------------------------------------------------------
__global__ __launch_bounds__(256) void k_node_mfma(
    const ushort* __restrict__ Apre, const ushort* __restrict__ W1T,
    const ushort* __restrict__ W2T, const float* __restrict__ b1,
    const float* __restrict__ b2,
    unsigned* __restrict__ hwq, unsigned* __restrict__ rtb)
{
    // unified LDS: sA[64*104] | sW1[64*104] | sW2[128*72] | sH[4*16*72]
    __shared__ __align__(16) ushort smem[27136];
    __shared__ float sb1[HID], sb2[OUTC];
    ushort* sA  = smem;
    ushort* sW1 = smem + 6656;
    ushort* sW2 = smem + 13312;
    ushort* sH  = smem + 22528;
    float*  sGf = (float*)smem;   // 64*120 f32 = 30720 B (aliases sA|sW1|part of sW2)

    int t = threadIdx.x;
    int nbase = blockIdx.x * 64;

#pragma unroll
    for (int i = 0; i < 3; i++) {
        int idx = t + i * 256;
        int row = idx / 12, c = idx % 12;
        uint4 v = make_uint4(0, 0, 0, 0);
        if (nbase + row < NN)
            v = *(const uint4*)(Apre + (size_t)(nbase + row) * 96 + c * 8);
        *(uint4*)(sA + row * 104 + c * 8) = v;
    }
#pragma unroll
    for (int i = 0; i < 3; i++) {
        int idx = t + i * 256;
        int row = idx / 12, c = idx % 12;
        *(uint4*)(sW1 + row * 104 + c * 8) =
            *(const uint4*)(W1T + row * 96 + c * 8);
    }
#pragma unroll
    for (int i = 0; i < 4; i++) {
        int idx = t + i * 256;
        int row = idx / 8, c = idx % 8;
        *(uint4*)(sW2 + row * 72 + c * 8) =
            *(const uint4*)(W2T + row * 64 + c * 8);
    }
    if (t < HID) sb1[t] = b1[t];
    if (t >= 64 && t < 64 + OUTC) sb2[t - 64] = b2[t - 64];
    __syncthreads();

    int w = t >> 6, lane = t & 63;
    int lm = lane & 15, lk = lane >> 4;

    // GEMM1: nodes [w*16, w*16+16), K=96
    f32x4 acc[4];
#pragma unroll
    for (int nt = 0; nt < 4; nt++) acc[nt] = (f32x4){0.f, 0.f, 0.f, 0.f};
#pragma unroll
    for (int kk = 0; kk < 3; kk++) {
        bf16x8 af = *(const bf16x8*)(sA + (w * 16 + lm) * 104 + kk * 32 + lk * 8);
#pragma unroll
        for (int nt = 0; nt < 4; nt++) {
            bf16x8 bfr = *(const bf16x8*)(sW1 + (nt * 16 + lm) * 104 + kk * 32 + lk * 8);
            acc[nt] = __builtin_amdgcn_mfma_f32_16x16x32_bf16(af, bfr, acc[nt], 0, 0, 0);
        }
    }

    // epilogue 1: +b1, ELU, write h tile (wave-local)
    ushort* hrow = sH + w * 16 * 72;
#pragma unroll
    for (int nt = 0; nt < 4; nt++) {
#pragma unroll
        for (int r = 0; r < 4; r++) {
            float v = acc[nt][r] + sb1[nt * 16 + lm];
            v = (v > 0.0f) ? v : (expf(v) - 1.0f);
            hrow[(lk * 4 + r) * 72 + nt * 16 + lm] = (ushort)f2bf(v);
        }
    }
    __syncthreads();   // all GEMM1 reads of sA/sW1 done

    // GEMM2: h[16x64] @ W2T^T -> 16 x 128, K=64
    f32x4 g[8];
#pragma unroll
    for (int nt = 0; nt < 8; nt++) g[nt] = (f32x4){0.f, 0.f, 0.f, 0.f};
#pragma unroll
    for (int kk = 0; kk < 2; kk++) {
        bf16x8 af = *(const bf16x8*)(hrow + lm * 72 + kk * 32 + lk * 8);
#pragma unroll
        for (int nt = 0; nt < 8; nt++) {
            bf16x8 bfr = *(const bf16x8*)(sW2 + (nt * 16 + lm) * 72 + kk * 32 + lk * 8);
            g[nt] = __builtin_amdgcn_mfma_f32_16x16x32_bf16(af, bfr, g[nt], 0, 0, 0);
        }
    }
    __syncthreads();   // sW2 reads done before sGf (stride-120) clobbers it

    // epilogue 2: stage into sGf[nl][120]: g0 at 0..39, d at 40..79, rt 80..119
#pragma unroll
    for (int nt = 0; nt < 8; nt++) {
        int j = nt * 16 + lm;
        int s = -1;
        if (j < 80) {
            int o = (j >> 3) * 4 + (j & 3);
            s = ((j & 7) < 4) ? o : (40 + o);
        } else if (j < 120) {
            s = j;
        }
#pragma unroll
        for (int r = 0; r < 4; r++) {
            int nl = w * 16 + lk * 4 + r;
            if (s >= 0) sGf[nl * 120 + s] = g[nt][r];
        }
    }
    __syncthreads();

    // repack: hwq uint k (k even: g0 quad k/2, k odd: d quad k>>1) + rtb f16
    for (int idx = t; idx < 64 * 40; idx += 256) {
        int nl = idx / 40, k = idx % 40;
        int node = nbase + nl;
        if (node >= NN) continue;
        if (k < 20) {
            const float* gp = sGf + nl * 120 + (k & 1) * 40 + (k >> 1) * 4;
            unsigned u = __builtin_amdgcn_cvt_pk_fp8_f32(gp[0], gp[1], 0, false);
            u = __builtin_amdgcn_cvt_pk_fp8_f32(gp[2], gp[3], u, true);
            hwq[(size_t)node * 20 + k] = u;
        } else {
            int q = k - 20;
            float v0 = sGf[nl * 120 + 80 + 2 * q]     + sb2[2 * q];
            float v1 = sGf[nl * 120 + 80 + 2 * q + 1] + sb2[2 * q + 1];
            rtb[(size_t)node * 20 + q] = (unsigned)f2h(v0) | ((unsigned)f2h(v1) << 16);
        }
    }
}

// ---------------------------------------------------------------------------
// Layer 2: wave per node, 12 edges per vmem instruction (5 lanes x uint4 =
// 16 fp8 = quads 2m,2m+1 of g0 and d -> outputs 8m..8m+7).
// msg = g0 + p*d in pk-f32; fold 12 slots; + rt (f16); log_softmax.
// ---------------------------------------------------------------------------
__global__ __launch_bounds__(256) void k_agg2f(
    const unsigned* __restrict__ hwq, const unsigned* __restrict__ rtb,
    const unsigned* __restrict__ pay, const int* __restrict__ offs,
    const int* __restrict__ cnt, float* __restrict__ out)
{
    __shared__ float scr[4][OUTC];
    int t = threadIdx.x;
    int w = t >> 6, lane = t & 63;
    int slot = lane / 5;             // 0..11 active, 12 = lanes 60-63
    int m = lane - slot * 5;         // 0..4 -> outputs 8m..8m+7

    for (int n0 = blockIdx.x * 4; n0 < NN; n0 += gridDim.x * 4) {
        int n = n0 + w;
        int e0 = offs[n], c = cnt[n];

        v2f a01 = {0.f, 0.f}, a23 = {0.f, 0.f}, a45 = {0.f, 0.f}, a67 = {0.f, 0.f};
        for (int base = 0; base < c; base += 64) {
            int bc = min(c - base, 64);
            int li = (lane < bc) ? lane : (bc - 1);
            unsigned pl = pay[e0 + base + li];
            for (int g = 0; g < bc; g += 12) {
                int je = g + slot;
                unsigned v = (unsigned)__shfl((int)pl, je & 63);
                bool valid = (slot < 12) && (je < bc);
                int sj = valid ? pdec_s(v) : NN;        // invalid -> zero row
                float pj = pdec_p(v);
                v2f pp = {pj, pj};
                uint4 gv = *((const uint4*)(hwq + (size_t)sj * 20) + m);
                // uint 4m+0: g0 quad 2m | 4m+1: d quad 2m | 4m+2: g0 quad 2m+1 | 4m+3: d quad 2m+1
                a01 += __builtin_elementwise_fma(pp, __builtin_amdgcn_cvt_pk_f32_fp8(gv.y, false),
                                                 __builtin_amdgcn_cvt_pk_f32_fp8(gv.x, false));
                a23 += __builtin_elementwise_fma(pp, __builtin_amdgcn_cvt_pk_f32_fp8(gv.y, true),
                                                 __builtin_amdgcn_cvt_pk_f32_fp8(gv.x, true));
                a45 += __builtin_elementwise_fma(pp, __builtin_amdgcn_cvt_pk_f32_fp8(gv.w, false),
                                                 __builtin_amdgcn_cvt_pk_f32_fp8(gv.z, false));
                a67 += __builtin_elementwise_fma(pp, __builtin_amdgcn_cvt_pk_f32_fp8(gv.w, true),
                                                 __builtin_amdgcn_cvt_pk_f32_fp8(gv.z, true));
            }
        }

        // fold 12 slots: +30 (s += s+6), +15 (s += s+3), then s0 += s1+s2
        a01 += sh2(a01, lane + 30); a23 += sh2(a23, lane + 30);
        a45 += sh2(a45, lane + 30); a67 += sh2(a67, lane + 30);
        a01 += sh2(a01, lane + 15); a23 += sh2(a23, lane + 15);
        a45 += sh2(a45, lane + 15); a67 += sh2(a67, lane + 15);
        {
            v2f u0 = a01, u1 = a23, u2 = a45, u3 = a67;
            a01 += sh2(u0, lane + 5) + sh2(u0, lane + 10);
            a23 += sh2(u1, lane + 5) + sh2(u1, lane + 10);
            a45 += sh2(u2, lane + 5) + sh2(u2, lane + 10);
            a67 += sh2(u3, lane + 5) + sh2(u3, lane + 10);
        }

        asm volatile("" ::: "memory");
        if (lane < 5) {
            scr[w][8 * m]     = a01.x; scr[w][8 * m + 1] = a01.y;
            scr[w][8 * m + 2] = a23.x; scr[w][8 * m + 3] = a23.y;
            scr[w][8 * m + 4] = a45.x; scr[w][8 * m + 5] = a45.y;
            scr[w][8 * m + 6] = a67.x; scr[w][8 * m + 7] = a67.y;
        }
        asm volatile("" ::: "memory");

        float inv = 1.0f / fmaxf((float)c, 1.0f);
        float r = 0.0f;
        if (lane < OUTC) {
            f16x2 hv = u2h(rtb[(size_t)n * 20 + (lane >> 1)]);
            float rv = (float)((lane & 1) ? hv[1] : hv[0]);
            r = fmaf(scr[w][lane], inv, rv);
        }

        float mx = (lane < OUTC) ? r : -1e30f;
#pragma unroll
        for (int off = 32; off > 0; off >>= 1) mx = fmaxf(mx, __shfl_xor(mx, off));
        float ex = (lane < OUTC) ? expf(r - mx) : 0.0f;
#pragma unroll
        for (int off = 32; off > 0; off >>= 1) ex += __shfl_xor(ex, off);
        float lse = mx + logf(ex);

        if (lane < OUTC) out[(size_t)n * OUTC + lane] = r - lse;
    }
}

// ---------------------------------------------------------------------------
extern "C" void kernel_launch(void* const* d_in, const int* in_sizes, int n_in,
                              void* d_out, int out_size, void* d_ws, size_t ws_size,
                              hipStream_t stream)
{
    const float* x     = (const float*)d_in[0];
    const int*   ei    = (const int*)  d_in[1];
    const float* ea    = (const float*)d_in[2];
    const float* W1    = (const float*)d_in[3];
    const float* root1 = (const float*)d_in[4];
    const float* b1    = (const float*)d_in[5];
    const float* W2    = (const float*)d_in[6];
    const float* root2 = (const float*)d_in[7];
    const float* b2    = (const float*)d_in[8];
    float* out = (float*)d_out;

    const int* src = ei;
    const int* dst = ei + NE;

    // workspace layout (~62 MB)
    char* wsp = (char*)d_ws;
    int*  cnt   = (int*)wsp;  wsp += sizeof(int) * NN;
    int*  offs  = (int*)wsp;  wsp += sizeof(int) * NN;
    int*  gcur  = (int*)wsp;  wsp += sizeof(int) * 512;
    int*  bbase = (int*)wsp;  wsp += sizeof(int) * 512;
    unsigned* pay = (unsigned*)wsp; wsp += sizeof(unsigned) * NE;                     // 6.4 MB
    unsigned* xq  = (unsigned*)wsp; wsp += sizeof(unsigned) * (size_t)(NN + 1) * 8;   // 3.2 MB
    ushort* Apre  = (ushort*)wsp; wsp += sizeof(ushort) * (size_t)NN * 96;            // 19.2 MB
    unsigned* hwq = (unsigned*)wsp; wsp += sizeof(unsigned) * (size_t)(NN + 1) * 20;  // 8 MB
    unsigned* rtb = (unsigned*)wsp; wsp += sizeof(unsigned) * (size_t)NN * 20;        // 8 MB
    ushort* W1T   = (ushort*)wsp; wsp += sizeof(ushort) * 64 * 96;
    ushort* W2T   = (ushort*)wsp; wsp += sizeof(ushort) * 128 * 64;
    wsp = (char*)(((size_t)wsp + 15) & ~(size_t)15);
    uint2* slab   = (uint2*)wsp; wsp += sizeof(uint2) * (size_t)NBUCK * BCAP;         // 16 MB

    hipMemsetAsync(gcur, 0, sizeof(int) * 512, stream);
    hipMemsetAsync(hwq + (size_t)NN * 20, 0, 80, stream);   // zero row

    int nprep = ((NN + 1) * 8 + 64 * 96 + 128 * 64 + 255) / 256;
    k_prep  <<<nprep, 256, 0, stream>>>(x, W1, root1, W2, root2, xq, W1T, W2T);
    k_bin   <<<(NE + 4095) / 4096, 256, 0, stream>>>(src, dst, ea, gcur, slab);
    k_bscan <<<1, 512, 0, stream>>>(gcur, bbase);
    k_csr   <<<NBUCK, 256, 0, stream>>>(slab, gcur, bbase, cnt, offs, pay);

    k_agg1  <<<2048, 256, 0, stream>>>(xq, pay, offs, cnt, x, Apre);
    k_node_mfma<<<(NN + 63) / 64, 256, 0, stream>>>(Apre, W1T, W2T, b1, b2, hwq, rtb);
    k_agg2f <<<2048, 256, 0, stream>>>(hwq, rtb, pay, offs, cnt, out);
}

// Round 15
// 171.127 us; speedup vs baseline: 1.1105x; 1.1105x over previous
//
#include <hip/hip_runtime.h>
#include <math.h>

#define NN   100000
#define NE   1600000
#define INC  32
#define HID  64
#define OUTC 40
#define NBUCK 391          // ceil(NN/256) coarse dst-buckets (256 nodes each)
#define BCAP  5120         // slab capacity per bucket (mean 4096, +16 sigma)

typedef short bf16x8 __attribute__((ext_vector_type(8)));
typedef float f32x4  __attribute__((ext_vector_type(4)));
typedef float v2f    __attribute__((ext_vector_type(2)));
typedef _Float16 f16x2 __attribute__((ext_vector_type(2)));

// bf16 helpers (round-to-nearest-even)
__device__ inline unsigned f2bf(float f) {
    unsigned u = __float_as_uint(f);
    return (u + 0x7fffu + ((u >> 16) & 1u)) >> 16;
}
__device__ inline unsigned packbf(float a, float b) {
    return f2bf(a) | (f2bf(b) << 16);
}
__device__ inline ushort f2h(float f) {
    return __builtin_bit_cast(unsigned short, (_Float16)f);
}
__device__ inline f16x2 u2h(unsigned u) { return __builtin_bit_cast(f16x2, u); }

// payload decode: src in bits 0-16, p (15-bit fixed) in bits 17-31
__device__ inline int   pdec_s(unsigned v) { return (int)(v & 0x1FFFFu); }
__device__ inline float pdec_p(unsigned v) { return (float)(v >> 17) * (1.0f / 32767.0f); }

// ---------------------------------------------------------------------------
// Binning pass: block-local histogram + one global atomicAdd per bucket per
// block, then run-writes of 8B payloads into per-bucket slabs.
// ---------------------------------------------------------------------------
__global__ __launch_bounds__(256) void k_bin(
    const int* __restrict__ src, const int* __restrict__ dst,
    const float* __restrict__ pseudo,
    int* __restrict__ gcur, uint2* __restrict__ slab)
{
    __shared__ int lh[NBUCK];
    __shared__ int lb[NBUCK];
    int t = threadIdx.x;
    for (int i = t; i < NBUCK; i += 256) lh[i] = 0;
    __syncthreads();

    int base = blockIdx.x * 4096;
#pragma unroll
    for (int i = 0; i < 16; i++) {
        int e = base + i * 256 + t;
        if (e < NE) atomicAdd(&lh[dst[e] >> 8], 1);
    }
    __syncthreads();
    for (int i = t; i < NBUCK; i += 256) {
        int c = lh[i];
        lb[i] = c ? atomicAdd(&gcur[i], c) : 0;
        lh[i] = 0;
    }
    __syncthreads();
#pragma unroll
    for (int i = 0; i < 16; i++) {
        int e = base + i * 256 + t;
        if (e < NE) {
            int d = dst[e];
            int b = d >> 8;
            int loc = atomicAdd(&lh[b], 1);
            unsigned pq = (unsigned)__float2int_rn(pseudo[e] * 32767.0f);
            slab[(size_t)b * BCAP + lb[b] + loc] =
                make_uint2((unsigned)src[e] | (pq << 17), (unsigned)(d & 255));
        }
    }
}

// exclusive scan of bucket sizes (one block)
__global__ __launch_bounds__(512) void k_bscan(const int* __restrict__ gcur,
                                               int* __restrict__ bbase)
{
    __shared__ int tmp[512];
    int t = threadIdx.x;
    int v = (t < NBUCK) ? gcur[t] : 0;
    tmp[t] = v;
    __syncthreads();
    for (int off = 1; off < 512; off <<= 1) {
        int add = (t >= off) ? tmp[t - off] : 0;
        __syncthreads();
        tmp[t] += add;
        __syncthreads();
    }
    if (t < NBUCK) bbase[t] = tmp[t] - v;
}

// Per-bucket CSR finalize: counts, offsets, and dst-ordered 4B payloads.
__global__ __launch_bounds__(256) void k_csr(
    const uint2* __restrict__ slab, const int* __restrict__ gcur,
    const int* __restrict__ bbase,
    int* __restrict__ cnt, int* __restrict__ offs, unsigned* __restrict__ pay)
{
    __shared__ int cl[256], ol[256], cur[256];
    __shared__ int ssz, sbase;
    int b = blockIdx.x, t = threadIdx.x;
    if (t == 0) { ssz = gcur[b]; sbase = bbase[b]; }
    cl[t] = 0;
    __syncthreads();
    int sz = ssz, base0 = sbase;
    const uint2* sl = slab + (size_t)b * BCAP;

    for (int i = t; i < sz; i += 256) atomicAdd(&cl[sl[i].y], 1);
    __syncthreads();

    int v = cl[t];
    ol[t] = v;
    __syncthreads();
    for (int off = 1; off < 256; off <<= 1) {
        int add = (t >= off) ? ol[t - off] : 0;
        __syncthreads();
        ol[t] += add;
        __syncthreads();
    }
    int excl = ol[t] - v;
    __syncthreads();
    ol[t] = excl;
    cur[t] = 0;
    int node = b * 256 + t;
    if (node < NN) { cnt[node] = v; offs[node] = base0 + excl; }
    __syncthreads();

    for (int i = t; i < sz; i += 256) {
        uint2 v2 = sl[i];
        int loc = atomicAdd(&cur[v2.y], 1);
        pay[base0 + ol[v2.y] + loc] = v2.x;
    }
}

// ---------------------------------------------------------------------------
// Merged prep: x -> fp8 rows (32 B/row, row NN zeroed) + weight transposes.
//  W1T[64][96]: k<32 -> W1[0]; 32<=k<64 -> W1[1]-W1[0]; k>=64 -> root1 (^T)
//  W2T[128][64]: col j<80: o=(j>>3)*4+(j&3); (j&7)<4 -> W2[0][:,o],
//                else W2[1][:,o]-W2[0][:,o]; 80..119: root2; 120..127: 0
// ---------------------------------------------------------------------------
__global__ __launch_bounds__(256) void k_prep(
    const float* __restrict__ x,
    const float* __restrict__ W1, const float* __restrict__ root1,
    const float* __restrict__ W2, const float* __restrict__ root2,
    unsigned* __restrict__ xq, ushort* __restrict__ W1T,
    ushort* __restrict__ W2T)
{
    int i = blockIdx.x * 256 + threadIdx.x;
    if (i < (NN + 1) * 8) {
        unsigned u = 0;
        if (i < NN * 8) {
            float4 v = ((const float4*)x)[i];
            u = __builtin_amdgcn_cvt_pk_fp8_f32(v.x, v.y, 0, false);
            u = __builtin_amdgcn_cvt_pk_fp8_f32(v.z, v.w, u, true);
        }
        xq[i] = u;
        return;
    }
    int j = i - (NN + 1) * 8;
    if (j >= 0 && j < 64 * 96) {
        int o = j / 96, k = j % 96;
        float v;
        if (k < 32)      v = W1[k * HID + o];
        else if (k < 64) v = W1[INC * HID + (k - 32) * HID + o] - W1[(k - 32) * HID + o];
        else             v = root1[(k - 64) * HID + o];
        W1T[j] = (ushort)f2bf(v);
    }
    int j2 = j - 64 * 96;
    if (j2 >= 0 && j2 < 128 * 64) {
        int jj = j2 / 64, k = j2 % 64;
        float v = 0.0f;
        if (jj < 80) {
            int o = (jj >> 3) * 4 + (jj & 3);
            float g0 = W2[k * OUTC + o];
            v = ((jj & 7) < 4) ? g0 : (W2[HID * OUTC + k * OUTC + o] - g0);
        } else if (jj < 120) {
            v = root2[k * OUTC + (jj - 80)];
        }
        W2T[j2] = (ushort)f2bf(v);
    }
}

// ---------------------------------------------------------------------------
// Layer 1 gather (R9 form): wave per node, 8 edges per vmem instruction; lane
// reads one dword = 4 fp8 feats. S=sum(x), T=sum(p*x) in packed f32.
// Apre = [S*inv | T*inv | x(f32 source)] (bf16).
// ---------------------------------------------------------------------------
__global__ __launch_bounds__(256) void k_agg1(
    const unsigned* __restrict__ xq, const unsigned* __restrict__ pay,
    const int* __restrict__ offs, const int* __restrict__ cnt,
    const float* __restrict__ x, ushort* __restrict__ Apre)
{
    int t = threadIdx.x;
    int w = t >> 6, lane = t & 63;
    int slot = lane >> 3, sub = lane & 7;

    for (int n0 = blockIdx.x * 4; n0 < NN; n0 += gridDim.x * 4) {
        int n = n0 + w;
        int e0 = offs[n], c = cnt[n];

        v2f S01 = {0.f, 0.f}, S23 = {0.f, 0.f};
        v2f T01 = {0.f, 0.f}, T23 = {0.f, 0.f};

        for (int base = 0; base < c; base += 64) {
            int bc = min(c - base, 64);
            int li = (lane < bc) ? lane : (bc - 1);
            unsigned pl = pay[e0 + base + li];
            for (int g = 0; g < bc; g += 8) {
                int je = g + slot;                       // <= 63
                unsigned v = (unsigned)__shfl((int)pl, je);
                int sj = (je < bc) ? pdec_s(v) : NN;     // invalid -> zero row
                float pj = pdec_p(v);
                v2f pp = {pj, pj};
                unsigned gv = xq[sj * 8 + sub];
                v2f v01 = __builtin_amdgcn_cvt_pk_f32_fp8(gv, false);
                v2f v23 = __builtin_amdgcn_cvt_pk_f32_fp8(gv, true);
                S01 += v01; S23 += v23;
                T01 = __builtin_elementwise_fma(pp, v01, T01);
                T23 = __builtin_elementwise_fma(pp, v23, T23);
            }
        }

        // butterfly over 8 slots (lane bits 3..5)
#pragma unroll
        for (int mask = 8; mask <= 32; mask <<= 1) {
            S01.x += __shfl_xor(S01.x, mask); S01.y += __shfl_xor(S01.y, mask);
            S23.x += __shfl_xor(S23.x, mask); S23.y += __shfl_xor(S23.y, mask);
            T01.x += __shfl_xor(T01.x, mask); T01.y += __shfl_xor(T01.y, mask);
            T23.x += __shfl_xor(T23.x, mask); T23.y += __shfl_xor(T23.y, mask);
        }
        if (slot == 0) {
            float inv = 1.0f / fmaxf((float)c, 1.0f);
            ushort* ap = Apre + (size_t)n * 96;
            *(uint2*)(ap + sub * 4) = make_uint2(
                packbf(S01.x * inv, S01.y * inv), packbf(S23.x * inv, S23.y * inv));
            *(uint2*)(ap + 32 + sub * 4) = make_uint2(
                packbf(T01.x * inv, T01.y * inv), packbf(T23.x * inv, T23.y * inv));
            float4 xv = *((const float4*)(x + (size_t)n * INC) + sub);
            *(uint2*)(ap + 64 + sub * 4) = make_uint2(
                packbf(xv.x, xv.y), packbf(xv.z, xv.w));
        }
    }
}

// ---------------------------------------------------------------------------
// Node transform on MFMA: 64 nodes/block, 4 waves x 16-node M-tiles.
// GEMM1 -> h (bf16 LDS); GEMM2 -> hwq (fp8 interleaved [g0-quad|d-quad], 80B
// rows) + rtb (packed f16 pairs of h@root2+b2, 80B rows), via LDS staging.
// ---------------------------------------------------------------------------
__global__ __launch_bounds__(256) void k_node_mfma(
    const ushort* __restrict__ Apre, const ushort* __restrict__ W1T,
    const ushort* __restrict__ W2T, const float* __restrict__ b1,
    const float* __restrict__ b2,
    unsigned* __restrict__ hwq, unsigned* __restrict__ rtb)
{
    // unified LDS: sA[64*104] | sW1[64*104] | sW2[128*72] | sH[4*16*72]
    __shared__ __align__(16) ushort smem[27136];
    __shared__ float sb1[HID], sb2[OUTC];
    ushort* sA  = smem;
    ushort* sW1 = smem + 6656;
    ushort* sW2 = smem + 13312;
    ushort* sH  = smem + 22528;
    float*  sGf = (float*)smem;   // 64*120 f32 = 30720 B (aliases sA|sW1|part of sW2)

    int t = threadIdx.x;
    int nbase = blockIdx.x * 64;

#pragma unroll
    for (int i = 0; i < 3; i++) {
        int idx = t + i * 256;
        int row = idx / 12, c = idx % 12;
        uint4 v = make_uint4(0, 0, 0, 0);
        if (nbase + row < NN)
            v = *(const uint4*)(Apre + (size_t)(nbase + row) * 96 + c * 8);
        *(uint4*)(sA + row * 104 + c * 8) = v;
    }
#pragma unroll
    for (int i = 0; i < 3; i++) {
        int idx = t + i * 256;
        int row = idx / 12, c = idx % 12;
        *(uint4*)(sW1 + row * 104 + c * 8) =
            *(const uint4*)(W1T + row * 96 + c * 8);
    }
#pragma unroll
    for (int i = 0; i < 4; i++) {
        int idx = t + i * 256;
        int row = idx / 8, c = idx % 8;
        *(uint4*)(sW2 + row * 72 + c * 8) =
            *(const uint4*)(W2T + row * 64 + c * 8);
    }
    if (t < HID) sb1[t] = b1[t];
    if (t >= 64 && t < 64 + OUTC) sb2[t - 64] = b2[t - 64];
    __syncthreads();

    int w = t >> 6, lane = t & 63;
    int lm = lane & 15, lk = lane >> 4;

    // GEMM1: nodes [w*16, w*16+16), K=96
    f32x4 acc[4];
#pragma unroll
    for (int nt = 0; nt < 4; nt++) acc[nt] = (f32x4){0.f, 0.f, 0.f, 0.f};
#pragma unroll
    for (int kk = 0; kk < 3; kk++) {
        bf16x8 af = *(const bf16x8*)(sA + (w * 16 + lm) * 104 + kk * 32 + lk * 8);
#pragma unroll
        for (int nt = 0; nt < 4; nt++) {
            bf16x8 bfr = *(const bf16x8*)(sW1 + (nt * 16 + lm) * 104 + kk * 32 + lk * 8);
            acc[nt] = __builtin_amdgcn_mfma_f32_16x16x32_bf16(af, bfr, acc[nt], 0, 0, 0);
        }
    }

    // epilogue 1: +b1, ELU, write h tile (wave-local)
    ushort* hrow = sH + w * 16 * 72;
#pragma unroll
    for (int nt = 0; nt < 4; nt++) {
#pragma unroll
        for (int r = 0; r < 4; r++) {
            float v = acc[nt][r] + sb1[nt * 16 + lm];
            v = (v > 0.0f) ? v : (__expf(v) - 1.0f);
            hrow[(lk * 4 + r) * 72 + nt * 16 + lm] = (ushort)f2bf(v);
        }
    }
    __syncthreads();   // all GEMM1 reads of sA/sW1 done

    // GEMM2: h[16x64] @ W2T^T -> 16 x 128, K=64
    f32x4 g[8];
#pragma unroll
    for (int nt = 0; nt < 8; nt++) g[nt] = (f32x4){0.f, 0.f, 0.f, 0.f};
#pragma unroll
    for (int kk = 0; kk < 2; kk++) {
        bf16x8 af = *(const bf16x8*)(hrow + lm * 72 + kk * 32 + lk * 8);
#pragma unroll
        for (int nt = 0; nt < 8; nt++) {
            bf16x8 bfr = *(const bf16x8*)(sW2 + (nt * 16 + lm) * 72 + kk * 32 + lk * 8);
            g[nt] = __builtin_amdgcn_mfma_f32_16x16x32_bf16(af, bfr, g[nt], 0, 0, 0);
        }
    }
    __syncthreads();   // sW2 reads done before sGf (stride-120) clobbers it

    // epilogue 2: stage into sGf[nl][120]: g0 at 0..39, d at 40..79, rt 80..119
#pragma unroll
    for (int nt = 0; nt < 8; nt++) {
        int j = nt * 16 + lm;
        int s = -1;
        if (j < 80) {
            int o = (j >> 3) * 4 + (j & 3);
            s = ((j & 7) < 4) ? o : (40 + o);
        } else if (j < 120) {
            s = j;
        }
#pragma unroll
        for (int r = 0; r < 4; r++) {
            int nl = w * 16 + lk * 4 + r;
            if (s >= 0) sGf[nl * 120 + s] = g[nt][r];
        }
    }
    __syncthreads();

    // repack: hwq uint k (k even: g0 quad k/2, k odd: d quad k>>1) + rtb f16
    for (int idx = t; idx < 64 * 40; idx += 256) {
        int nl = idx / 40, k = idx % 40;
        int node = nbase + nl;
        if (node >= NN) continue;
        if (k < 20) {
            const float* gp = sGf + nl * 120 + (k & 1) * 40 + (k >> 1) * 4;
            unsigned u = __builtin_amdgcn_cvt_pk_fp8_f32(gp[0], gp[1], 0, false);
            u = __builtin_amdgcn_cvt_pk_fp8_f32(gp[2], gp[3], u, true);
            hwq[(size_t)node * 20 + k] = u;
        } else {
            int q = k - 20;
            float v0 = sGf[nl * 120 + 80 + 2 * q]     + sb2[2 * q];
            float v1 = sGf[nl * 120 + 80 + 2 * q + 1] + sb2[2 * q + 1];
            rtb[(size_t)node * 20 + q] = (unsigned)f2h(v0) | ((unsigned)f2h(v1) << 16);
        }
    }
}

// ---------------------------------------------------------------------------
// Layer 2 (R9 form): wave per node, 6 edges per vmem instruction. Lane m
// reads uint2 = {g0-quad fp8, d-quad fp8} for outputs 4m..4m+3;
// msg = g0 + p*d in pk-f32. + rtb (f16), log_softmax with fast intrinsics.
// ---------------------------------------------------------------------------
__global__ __launch_bounds__(256) void k_agg2f(
    const unsigned* __restrict__ hwq, const unsigned* __restrict__ rtb,
    const unsigned* __restrict__ pay, const int* __restrict__ offs,
    const int* __restrict__ cnt, float* __restrict__ out)
{
    __shared__ float scr[4][OUTC];
    int t = threadIdx.x;
    int w = t >> 6, lane = t & 63;
    int slot = lane / 10;            // 0..5 active, 6 = lanes 60-63 (zero row)
    int m = lane - slot * 10;        // 0..9 -> outputs 4m..4m+3

    for (int n0 = blockIdx.x * 4; n0 < NN; n0 += gridDim.x * 4) {
        int n = n0 + w;
        int e0 = offs[n], c = cnt[n];

        v2f a01 = {0.f, 0.f}, a23 = {0.f, 0.f};
        for (int base = 0; base < c; base += 64) {
            int bc = min(c - base, 64);
            int li = (lane < bc) ? lane : (bc - 1);
            unsigned pl = pay[e0 + base + li];
            for (int g = 0; g < bc; g += 6) {
                int je = g + slot;
                unsigned v = (unsigned)__shfl((int)pl, je & 63);
                bool valid = (slot < 6) && (je < bc);
                int sj = valid ? pdec_s(v) : NN;        // invalid -> zero row
                float pj = pdec_p(v);
                v2f pp = {pj, pj};
                uint2 gv = *((const uint2*)(hwq + (size_t)sj * 20) + m);
                v2f g01 = __builtin_amdgcn_cvt_pk_f32_fp8(gv.x, false);
                v2f g23 = __builtin_amdgcn_cvt_pk_f32_fp8(gv.x, true);
                v2f d01 = __builtin_amdgcn_cvt_pk_f32_fp8(gv.y, false);
                v2f d23 = __builtin_amdgcn_cvt_pk_f32_fp8(gv.y, true);
                a01 += __builtin_elementwise_fma(pp, d01, g01);
                a23 += __builtin_elementwise_fma(pp, d23, g23);
            }
        }

        // fold 6 slots: +30, then +10 and +20
        a01.x += __shfl(a01.x, (lane + 30) & 63);
        a01.y += __shfl(a01.y, (lane + 30) & 63);
        a23.x += __shfl(a23.x, (lane + 30) & 63);
        a23.y += __shfl(a23.y, (lane + 30) & 63);
        {
            float u0 = a01.x, u1 = a01.y, u2 = a23.x, u3 = a23.y;
            a01.x += __shfl(u0, (lane + 10) & 63) + __shfl(u0, (lane + 20) & 63);
            a01.y += __shfl(u1, (lane + 10) & 63) + __shfl(u1, (lane + 20) & 63);
            a23.x += __shfl(u2, (lane + 10) & 63) + __shfl(u2, (lane + 20) & 63);
            a23.y += __shfl(u3, (lane + 10) & 63) + __shfl(u3, (lane + 20) & 63);
        }

        asm volatile("" ::: "memory");
        if (lane < 10) {
            scr[w][4 * m]     = a01.x;
            scr[w][4 * m + 1] = a01.y;
            scr[w][4 * m + 2] = a23.x;
            scr[w][4 * m + 3] = a23.y;
        }
        asm volatile("" ::: "memory");

        float inv = 1.0f / fmaxf((float)c, 1.0f);
        float r = 0.0f;
        if (lane < OUTC) {
            f16x2 hv = u2h(rtb[(size_t)n * 20 + (lane >> 1)]);
            float rv = (float)((lane & 1) ? hv[1] : hv[0]);
            r = fmaf(scr[w][lane], inv, rv);
        }

        float mx = (lane < OUTC) ? r : -1e30f;
#pragma unroll
        for (int off = 32; off > 0; off >>= 1) mx = fmaxf(mx, __shfl_xor(mx, off));
        float ex = (lane < OUTC) ? __expf(r - mx) : 0.0f;
#pragma unroll
        for (int off = 32; off > 0; off >>= 1) ex += __shfl_xor(ex, off);
        float lse = mx + __logf(ex);

        if (lane < OUTC) out[(size_t)n * OUTC + lane] = r - lse;
    }
}

// ---------------------------------------------------------------------------
extern "C" void kernel_launch(void* const* d_in, const int* in_sizes, int n_in,
                              void* d_out, int out_size, void* d_ws, size_t ws_size,
                              hipStream_t stream)
{
    const float* x     = (const float*)d_in[0];
    const int*   ei    = (const int*)  d_in[1];
    const float* ea    = (const float*)d_in[2];
    const float* W1    = (const float*)d_in[3];
    const float* root1 = (const float*)d_in[4];
    const float* b1    = (const float*)d_in[5];
    const float* W2    = (const float*)d_in[6];
    const float* root2 = (const float*)d_in[7];
    const float* b2    = (const float*)d_in[8];
    float* out = (float*)d_out;

    const int* src = ei;
    const int* dst = ei + NE;

    // workspace layout (~62 MB)
    char* wsp = (char*)d_ws;
    int*  cnt   = (int*)wsp;  wsp += sizeof(int) * NN;
    int*  offs  = (int*)wsp;  wsp += sizeof(int) * NN;
    int*  gcur  = (int*)wsp;  wsp += sizeof(int) * 512;
    int*  bbase = (int*)wsp;  wsp += sizeof(int) * 512;
    unsigned* pay = (unsigned*)wsp; wsp += sizeof(unsigned) * NE;                     // 6.4 MB
    unsigned* xq  = (unsigned*)wsp; wsp += sizeof(unsigned) * (size_t)(NN + 1) * 8;   // 3.2 MB
    ushort* Apre  = (ushort*)wsp; wsp += sizeof(ushort) * (size_t)NN * 96;            // 19.2 MB
    unsigned* hwq = (unsigned*)wsp; wsp += sizeof(unsigned) * (size_t)(NN + 1) * 20;  // 8 MB
    unsigned* rtb = (unsigned*)wsp; wsp += sizeof(unsigned) * (size_t)NN * 20;        // 8 MB
    ushort* W1T   = (ushort*)wsp; wsp += sizeof(ushort) * 64 * 96;
    ushort* W2T   = (ushort*)wsp; wsp += sizeof(ushort) * 128 * 64;
    wsp = (char*)(((size_t)wsp + 15) & ~(size_t)15);
    uint2* slab   = (uint2*)wsp; wsp += sizeof(uint2) * (size_t)NBUCK * BCAP;         // 16 MB

    hipMemsetAsync(gcur, 0, sizeof(int) * 512, stream);
    hipMemsetAsync(hwq + (size_t)NN * 20, 0, 80, stream);   // zero row

    int nprep = ((NN + 1) * 8 + 64 * 96 + 128 * 64 + 255) / 256;
    k_prep  <<<nprep, 256, 0, stream>>>(x, W1, root1, W2, root2, xq, W1T, W2T);
    k_bin   <<<(NE + 4095) / 4096, 256, 0, stream>>>(src, dst, ea, gcur, slab);
    k_bscan <<<1, 512, 0, stream>>>(gcur, bbase);
    k_csr   <<<NBUCK, 256, 0, stream>>>(slab, gcur, bbase, cnt, offs, pay);

    k_agg1  <<<2048, 256, 0, stream>>>(xq, pay, offs, cnt, x, Apre);
    k_node_mfma<<<(NN + 63) / 64, 256, 0, stream>>>(Apre, W1T, W2T, b1, b2, hwq, rtb);
    k_agg2f <<<2048, 256, 0, stream>>>(hwq, rtb, pay, offs, cnt, out);
}